// Round 4
// baseline (159.806 us; speedup 1.0000x reference)
//
#include <hip/hip_runtime.h>
#include <math.h>

// Gaussian splatting forward rasterizer, MI355X.
// P=2048 gaussians, 128x128 image. Output: img (3*128*128 f32) ++ radii (P f32).
//
// R4: two fused kernels.
//  K1 prep_rank_scatter (32 blocks): every block computes all P depth keys in
//     LDS (redundant, trivial), stable-ranks its 64 gaussians (rank_i =
//     #{k_j<k_i} + #{j<i: k_j==k_i} == numpy stable argsort), computes the
//     full record and scatters to sorted slot. Record slot 9 = cull radius^2:
//     r2 = 2*ln(255*op)*lam_max -> d^2 > r2 implies alpha < 1/255 (exact,
//     since Mahalanobis q >= d^2/lam_max), i.e. culling matches the
//     reference's own skip condition.
//  K2 tile_raster (64 blocks, one per 16x16 tile): per 256-chunk, stage
//     records to LDS, per-thread tile-overlap predicate -> __ballot masks,
//     composite only set bits (uniform mask walk, broadcast LDS reads),
//     block-wide early exit at T < 1e-4 (residual error <= 1e-4 << 0.4 thr).

#define IMG 128
#define NPIX (IMG * IMG)
#define GS 12        // record: px py ca cb cc op r g b r2 pad pad
#define SORT_N 2048

// ---------------------------------------------------------- projection chain
__device__ __forceinline__ void gproj(int i,
                                      const float* __restrict__ means,
                                      const float* __restrict__ rots,
                                      const float* __restrict__ scales,
                                      const float* __restrict__ vm,
                                      const float* __restrict__ pm,
                                      float& depth, bool& valid,
                                      float& px, float& py,
                                      float& ca, float& cb, float& cc,
                                      float& lam)
{
    const float W = (float)IMG, H = (float)IMG;
    const float tanfov = 0.5773502691896258f;        // tan(FOV/2)
    const float focal_x = W / (2.0f * tanfov);
    const float focal_y = H / (2.0f * tanfov);
    const float lim = 1.3f * tanfov;

    float mx = means[3 * i + 0], my = means[3 * i + 1], mz = means[3 * i + 2];

    float tx = vm[0] * mx + vm[1] * my + vm[2]  * mz + vm[3];
    float ty = vm[4] * mx + vm[5] * my + vm[6]  * mz + vm[7];
    float tz = vm[8] * mx + vm[9] * my + vm[10] * mz + vm[11];
    depth = tz;

    float ph0 = pm[0]  * mx + pm[1]  * my + pm[2]  * mz + pm[3];
    float ph1 = pm[4]  * mx + pm[5]  * my + pm[6]  * mz + pm[7];
    float pw  = pm[12] * mx + pm[13] * my + pm[14] * mz + pm[15];
    float rinv = 1.0f / (pw + 1e-7f);
    px = ((ph0 * rinv + 1.0f) * W - 1.0f) * 0.5f;
    py = ((ph1 * rinv + 1.0f) * H - 1.0f) * 0.5f;

    float qw = rots[4 * i + 0], qx = rots[4 * i + 1], qy = rots[4 * i + 2], qz = rots[4 * i + 3];
    float qn = sqrtf(qw * qw + qx * qx + qy * qy + qz * qz);
    qw /= qn; qx /= qn; qy /= qn; qz /= qn;
    float R00 = 1.0f - 2.0f * (qy * qy + qz * qz), R01 = 2.0f * (qx * qy - qw * qz), R02 = 2.0f * (qx * qz + qw * qy);
    float R10 = 2.0f * (qx * qy + qw * qz), R11 = 1.0f - 2.0f * (qx * qx + qz * qz), R12 = 2.0f * (qy * qz - qw * qx);
    float R20 = 2.0f * (qx * qz - qw * qy), R21 = 2.0f * (qy * qz + qw * qx), R22 = 1.0f - 2.0f * (qx * qx + qy * qy);

    float sx = scales[3 * i + 0], sy = scales[3 * i + 1], sz = scales[3 * i + 2];
    float M00 = R00 * sx, M01 = R01 * sy, M02 = R02 * sz;
    float M10 = R10 * sx, M11 = R11 * sy, M12 = R12 * sz;
    float M20 = R20 * sx, M21 = R21 * sy, M22 = R22 * sz;
    float S00 = M00 * M00 + M01 * M01 + M02 * M02;
    float S01 = M00 * M10 + M01 * M11 + M02 * M12;
    float S02 = M00 * M20 + M01 * M21 + M02 * M22;
    float S11 = M10 * M10 + M11 * M11 + M12 * M12;
    float S12 = M10 * M20 + M11 * M21 + M12 * M22;
    float S22 = M20 * M20 + M21 * M21 + M22 * M22;

    float txc = fminf(fmaxf(tx / tz, -lim), lim) * tz;
    float tyc = fminf(fmaxf(ty / tz, -lim), lim) * tz;
    float J00 = focal_x / tz, J02 = -focal_x * txc / (tz * tz);
    float J11 = focal_y / tz, J12 = -focal_y * tyc / (tz * tz);

    float T00 = J00 * vm[0] + J02 * vm[8];
    float T01 = J00 * vm[1] + J02 * vm[9];
    float T02 = J00 * vm[2] + J02 * vm[10];
    float T10 = J11 * vm[4] + J12 * vm[8];
    float T11 = J11 * vm[5] + J12 * vm[9];
    float T12 = J11 * vm[6] + J12 * vm[10];

    float U00 = T00 * S00 + T01 * S01 + T02 * S02;
    float U01 = T00 * S01 + T01 * S11 + T02 * S12;
    float U02 = T00 * S02 + T01 * S12 + T02 * S22;
    float U10 = T10 * S00 + T11 * S01 + T12 * S02;
    float U11 = T10 * S01 + T11 * S11 + T12 * S12;
    float U12 = T10 * S02 + T11 * S12 + T12 * S22;
    float C00 = U00 * T00 + U01 * T01 + U02 * T02;
    float C01 = U00 * T10 + U01 * T11 + U02 * T12;
    float C11 = U10 * T10 + U11 * T11 + U12 * T12;

    float a = C00 + 0.3f, b = C01, c = C11 + 0.3f;
    float det = a * c - b * b;
    valid = (depth > 0.2f) && (det > 0.0f);
    float det_s = valid ? det : 1.0f;
    ca = c / det_s; cb = -b / det_s; cc = a / det_s;

    float mid = 0.5f * (a + c);
    lam = mid + sqrtf(fmaxf(mid * mid - det, 0.1f));
}

// ------------------------------------------- fused preprocess + rank + scatter
__global__ void gsplat_prep_rank_scatter(const float* __restrict__ means,
                                         const float* __restrict__ feats,
                                         const float* __restrict__ ops,
                                         const float* __restrict__ scales,
                                         const float* __restrict__ rots,
                                         const float* __restrict__ vm,
                                         const float* __restrict__ pm,
                                         float* __restrict__ gS,
                                         float* __restrict__ radii_out,
                                         int P)
{
    __shared__ unsigned int sk[SORT_N];
    __shared__ int partial[256];
    int tid = threadIdx.x;

    // Phase A: every block computes ALL depth keys (redundant but trivial).
    #pragma unroll 2
    for (int j = tid; j < SORT_N; j += 256) {
        unsigned int key = 0xFFFFFFFFu;                  // pad sorts last
        if (j < P) {
            float depth, px, py, ca, cb, cc, lam; bool valid;
            gproj(j, means, rots, scales, vm, pm, depth, valid, px, py, ca, cb, cc, lam);
            key = valid ? __float_as_uint(depth) : 0x7f800000u; // +inf for invalid
        }
        sk[j] = key;
    }
    __syncthreads();

    // Phase B: stable rank for this block's 64 gaussians (4 key-slices x 64).
    int g = tid & 63, s = tid >> 6;
    int i = blockIdx.x * 64 + g;
    bool act = (i < P);
    unsigned int ki = act ? sk[i] : 0u;

    const int SLICE = SORT_N / 4;
    int j0 = s * SLICE;
    const uint4* sk4 = (const uint4*)(sk + j0);
    int r = 0;
    #pragma unroll 4
    for (int q = 0; q < SLICE / 4; ++q) {
        uint4 k = sk4[q];                                // wave-broadcast
        int j = j0 + 4 * q;
        r += (k.x < ki) || (k.x == ki && (j + 0) < i);
        r += (k.y < ki) || (k.y == ki && (j + 1) < i);
        r += (k.z < ki) || (k.z == ki && (j + 2) < i);
        r += (k.w < ki) || (k.w == ki && (j + 3) < i);
    }
    partial[tid] = r;
    __syncthreads();

    // Phase C: full record for own gaussian -> sorted slot; radii in orig order.
    if (s == 0 && act) {
        int rank = partial[g] + partial[64 + g] + partial[128 + g] + partial[192 + g];

        float depth, px, py, ca, cb, cc, lam; bool valid;
        gproj(i, means, rots, scales, vm, pm, depth, valid, px, py, ca, cb, cc, lam);

        const float SH_C0 = 0.28209479177387814f;
        float colr = fmaxf(SH_C0 * feats[3 * i + 0] + 0.5f, 0.0f);
        float colg = fmaxf(SH_C0 * feats[3 * i + 1] + 0.5f, 0.0f);
        float colb = fmaxf(SH_C0 * feats[3 * i + 2] + 0.5f, 0.0f);

        float opv = ops[i];
        float r2;
        if (valid) {
            // alpha >= 1/255 requires d^2 <= 2*ln(255*op)*lam_max (exact bound)
            r2 = 2.0f * lam * __logf(255.0f * opv) * 1.02f + 0.5f;
        } else {
            px = 0.0f; py = 0.0f; ca = 0.0f; cb = 0.0f; cc = 0.0f;
            opv = 0.0f; r2 = -1.0f;                      // never composited
        }
        radii_out[i] = valid ? ceilf(3.0f * sqrtf(lam)) : 0.0f;

        float4* dst = (float4*)(gS + (size_t)rank * GS);
        dst[0] = make_float4(px, py, ca, cb);
        dst[1] = make_float4(cc, opv, colr, colg);
        dst[2] = make_float4(colb, r2, 0.0f, 0.0f);
    }
}

// -------------------------------------------------- fused tile raster+combine
// One block per 16x16 tile. Chunked LDS staging + exact cull ballot +
// uniform mask-walk composite + block-wide early exit.
__global__ void gsplat_tile_raster(const float* __restrict__ gS, int P,
                                   float* __restrict__ img)
{
    __shared__ float4 srec[256 * 3];                     // 12 KB
    __shared__ unsigned long long sball[4];

    int tid = threadIdx.x;
    int lane = tid & 63, wave = tid >> 6;
    int lx = tid & 15, ly = tid >> 4;
    int x0 = (blockIdx.x & 7) * 16, y0 = (blockIdx.x >> 3) * 16;
    float gx = (float)(x0 + lx), gy = (float)(y0 + ly);
    float tx0 = (float)x0, tx1 = (float)(x0 + 15);
    float ty0 = (float)y0, ty1 = (float)(y0 + 15);

    float T = 1.0f, cr = 0.0f, cg = 0.0f, cbl = 0.0f;
    bool done = false;

    for (int base = 0; base < P; base += 256) {
        __syncthreads();
        // stage 256 records (coalesced global, conflict-free LDS)
        const float4* src = (const float4*)(gS + (size_t)base * GS);
        #pragma unroll
        for (int t = tid; t < 768; t += 256) srec[t] = src[t];
        __syncthreads();

        // predicate: does gaussian `tid` of this chunk touch the tile?
        float4 f0 = srec[tid * 3];                       // px py ca cb
        float4 f2 = srec[tid * 3 + 2];                   // colb r2 - -
        float ddx = f0.x - fminf(fmaxf(f0.x, tx0), tx1);
        float ddy = f0.y - fminf(fmaxf(f0.y, ty0), ty1);
        int pred = (ddx * ddx + ddy * ddy) <= f2.y;
        unsigned long long m = __ballot(pred);
        if (lane == 0) sball[wave] = m;
        __syncthreads();

        if (!done) {
            #pragma unroll
            for (int ss = 0; ss < 4; ++ss) {
                unsigned long long mm = sball[ss];       // uniform across block
                while (mm) {
                    int b = __builtin_ctzll(mm); mm &= mm - 1;
                    int idx = (ss * 64 + b) * 3;
                    float4 a0 = srec[idx];               // broadcast reads
                    float4 a1 = srec[idx + 1];
                    float4 a2 = srec[idx + 2];
                    float dx = gx - a0.x, dy = gy - a0.y;
                    float power = -0.5f * (a0.z * dx * dx + a1.x * dy * dy) - a0.w * dx * dy;
                    float e = __expf(fminf(power, 0.0f));
                    float alpha = fminf(0.99f, a1.y * e);
                    alpha = (power > 0.0f) ? 0.0f : alpha;
                    alpha = (alpha < 0.00392156862745098f) ? 0.0f : alpha;
                    float w = T * alpha;
                    cr  = fmaf(w, a1.z, cr);
                    cg  = fmaf(w, a1.w, cg);
                    cbl = fmaf(w, a2.x, cbl);
                    T *= (1.0f - alpha);
                    if (T < 1e-4f) { done = true; break; }
                }
                if (done) break;
            }
        }
        if (__syncthreads_and((int)done)) break;
    }

    int pix = (y0 + ly) * IMG + (x0 + lx);
    img[pix]            = cr  + T;
    img[NPIX + pix]     = cg  + T;
    img[2 * NPIX + pix] = cbl + T;
}

// ------------------------------------------------------------------ launch
extern "C" void kernel_launch(void* const* d_in, const int* in_sizes, int n_in,
                              void* d_out, int out_size, void* d_ws, size_t ws_size,
                              hipStream_t stream)
{
    const float* means  = (const float*)d_in[0];
    const float* feats  = (const float*)d_in[2];
    const float* ops    = (const float*)d_in[3];
    const float* scales = (const float*)d_in[4];
    const float* rots   = (const float*)d_in[5];
    const float* vm     = (const float*)d_in[6];
    const float* pm     = (const float*)d_in[7];

    int P = in_sizes[0] / 3;   // 2048

    float* img   = (float*)d_out;            // 3*128*128
    float* radii = (float*)d_out + 3 * NPIX; // P

    float* gS = (float*)d_ws;                // SORT_N*GS floats (sorted records)

    gsplat_prep_rank_scatter<<<(P + 63) / 64, 256, 0, stream>>>(
        means, feats, ops, scales, rots, vm, pm, gS, radii, P);

    gsplat_tile_raster<<<64, 256, 0, stream>>>(gS, P, img);
}

// Round 5
// 124.265 us; speedup vs baseline: 1.2860x; 1.2860x over previous
//
#include <hip/hip_runtime.h>
#include <math.h>

// Gaussian splatting forward rasterizer, MI355X.
// P=2048 gaussians, 128x128 image. Output: img (3*128*128 f32) ++ radii (P f32).
//
// R5: R3's high-parallelism chunked raster (64 tiles x K=32 chunks = 2048
// blocks; R4's 64-block fused raster was occupancy-starved: 1 wave/SIMD,
// 68us) + R4's fused prep+rank+scatter (1 dispatch, no gU round-trip) +
// block-uniform r2 cull in the raster (record loads are scalar -> the
// tile-overlap test is wave-uniform, s_cbranch, zero divergence).
// r2 = 2*lam_max*ln(255*op): d^2 > r2 implies alpha < 1/255 (exact bound,
// Mahalanobis q >= d^2/lam_max), i.e. the reference skips it too.

#define IMG 128
#define NPIX (IMG * IMG)
#define GS 12        // record: px py ca cb cc op r g b r2 pad pad
#define SORT_N 2048

// ---------------------------------------------------------- projection chain
__device__ __forceinline__ void gproj(int i,
                                      const float* __restrict__ means,
                                      const float* __restrict__ rots,
                                      const float* __restrict__ scales,
                                      const float* __restrict__ vm,
                                      const float* __restrict__ pm,
                                      float& depth, bool& valid,
                                      float& px, float& py,
                                      float& ca, float& cb, float& cc,
                                      float& lam)
{
    const float W = (float)IMG, H = (float)IMG;
    const float tanfov = 0.5773502691896258f;        // tan(FOV/2)
    const float focal_x = W / (2.0f * tanfov);
    const float focal_y = H / (2.0f * tanfov);
    const float lim = 1.3f * tanfov;

    float mx = means[3 * i + 0], my = means[3 * i + 1], mz = means[3 * i + 2];

    float tx = vm[0] * mx + vm[1] * my + vm[2]  * mz + vm[3];
    float ty = vm[4] * mx + vm[5] * my + vm[6]  * mz + vm[7];
    float tz = vm[8] * mx + vm[9] * my + vm[10] * mz + vm[11];
    depth = tz;

    float ph0 = pm[0]  * mx + pm[1]  * my + pm[2]  * mz + pm[3];
    float ph1 = pm[4]  * mx + pm[5]  * my + pm[6]  * mz + pm[7];
    float pw  = pm[12] * mx + pm[13] * my + pm[14] * mz + pm[15];
    float rinv = 1.0f / (pw + 1e-7f);
    px = ((ph0 * rinv + 1.0f) * W - 1.0f) * 0.5f;
    py = ((ph1 * rinv + 1.0f) * H - 1.0f) * 0.5f;

    float qw = rots[4 * i + 0], qx = rots[4 * i + 1], qy = rots[4 * i + 2], qz = rots[4 * i + 3];
    float qn = sqrtf(qw * qw + qx * qx + qy * qy + qz * qz);
    qw /= qn; qx /= qn; qy /= qn; qz /= qn;
    float R00 = 1.0f - 2.0f * (qy * qy + qz * qz), R01 = 2.0f * (qx * qy - qw * qz), R02 = 2.0f * (qx * qz + qw * qy);
    float R10 = 2.0f * (qx * qy + qw * qz), R11 = 1.0f - 2.0f * (qx * qx + qz * qz), R12 = 2.0f * (qy * qz - qw * qx);
    float R20 = 2.0f * (qx * qz - qw * qy), R21 = 2.0f * (qy * qz + qw * qx), R22 = 1.0f - 2.0f * (qx * qx + qy * qy);

    float sx = scales[3 * i + 0], sy = scales[3 * i + 1], sz = scales[3 * i + 2];
    float M00 = R00 * sx, M01 = R01 * sy, M02 = R02 * sz;
    float M10 = R10 * sx, M11 = R11 * sy, M12 = R12 * sz;
    float M20 = R20 * sx, M21 = R21 * sy, M22 = R22 * sz;
    float S00 = M00 * M00 + M01 * M01 + M02 * M02;
    float S01 = M00 * M10 + M01 * M11 + M02 * M12;
    float S02 = M00 * M20 + M01 * M21 + M02 * M22;
    float S11 = M10 * M10 + M11 * M11 + M12 * M12;
    float S12 = M10 * M20 + M11 * M21 + M12 * M22;
    float S22 = M20 * M20 + M21 * M21 + M22 * M22;

    float txc = fminf(fmaxf(tx / tz, -lim), lim) * tz;
    float tyc = fminf(fmaxf(ty / tz, -lim), lim) * tz;
    float J00 = focal_x / tz, J02 = -focal_x * txc / (tz * tz);
    float J11 = focal_y / tz, J12 = -focal_y * tyc / (tz * tz);

    float T00 = J00 * vm[0] + J02 * vm[8];
    float T01 = J00 * vm[1] + J02 * vm[9];
    float T02 = J00 * vm[2] + J02 * vm[10];
    float T10 = J11 * vm[4] + J12 * vm[8];
    float T11 = J11 * vm[5] + J12 * vm[9];
    float T12 = J11 * vm[6] + J12 * vm[10];

    float U00 = T00 * S00 + T01 * S01 + T02 * S02;
    float U01 = T00 * S01 + T01 * S11 + T02 * S12;
    float U02 = T00 * S02 + T01 * S12 + T02 * S22;
    float U10 = T10 * S00 + T11 * S01 + T12 * S02;
    float U11 = T10 * S01 + T11 * S11 + T12 * S12;
    float U12 = T10 * S02 + T11 * S12 + T12 * S22;
    float C00 = U00 * T00 + U01 * T01 + U02 * T02;
    float C01 = U00 * T10 + U01 * T11 + U02 * T12;
    float C11 = U10 * T10 + U11 * T11 + U12 * T12;

    float a = C00 + 0.3f, b = C01, c = C11 + 0.3f;
    float det = a * c - b * b;
    valid = (depth > 0.2f) && (det > 0.0f);
    float det_s = valid ? det : 1.0f;
    ca = c / det_s; cb = -b / det_s; cc = a / det_s;

    float mid = 0.5f * (a + c);
    lam = mid + sqrtf(fmaxf(mid * mid - det, 0.1f));
}

// ------------------------------------------- fused preprocess + rank + scatter
__global__ void gsplat_prep_rank_scatter(const float* __restrict__ means,
                                         const float* __restrict__ feats,
                                         const float* __restrict__ ops,
                                         const float* __restrict__ scales,
                                         const float* __restrict__ rots,
                                         const float* __restrict__ vm,
                                         const float* __restrict__ pm,
                                         float* __restrict__ gS,
                                         float* __restrict__ radii_out,
                                         int P)
{
    __shared__ unsigned int sk[SORT_N];
    __shared__ int partial[256];
    int tid = threadIdx.x;

    // Phase A: every block computes ALL depth keys (redundant but trivial).
    #pragma unroll 2
    for (int j = tid; j < SORT_N; j += 256) {
        unsigned int key = 0xFFFFFFFFu;                  // pad sorts last
        if (j < P) {
            float depth, px, py, ca, cb, cc, lam; bool valid;
            gproj(j, means, rots, scales, vm, pm, depth, valid, px, py, ca, cb, cc, lam);
            key = valid ? __float_as_uint(depth) : 0x7f800000u; // +inf for invalid
        }
        sk[j] = key;
    }
    __syncthreads();

    // Phase B: stable rank for this block's 64 gaussians (4 key-slices x 64).
    int g = tid & 63, s = tid >> 6;
    int i = blockIdx.x * 64 + g;
    bool act = (i < P);
    unsigned int ki = act ? sk[i] : 0u;

    const int SLICE = SORT_N / 4;
    int j0 = s * SLICE;
    const uint4* sk4 = (const uint4*)(sk + j0);
    int r = 0;
    #pragma unroll 4
    for (int q = 0; q < SLICE / 4; ++q) {
        uint4 k = sk4[q];                                // wave-broadcast
        int j = j0 + 4 * q;
        r += (k.x < ki) || (k.x == ki && (j + 0) < i);
        r += (k.y < ki) || (k.y == ki && (j + 1) < i);
        r += (k.z < ki) || (k.z == ki && (j + 2) < i);
        r += (k.w < ki) || (k.w == ki && (j + 3) < i);
    }
    partial[tid] = r;
    __syncthreads();

    // Phase C: full record for own gaussian -> sorted slot; radii in orig order.
    if (s == 0 && act) {
        int rank = partial[g] + partial[64 + g] + partial[128 + g] + partial[192 + g];

        float depth, px, py, ca, cb, cc, lam; bool valid;
        gproj(i, means, rots, scales, vm, pm, depth, valid, px, py, ca, cb, cc, lam);

        const float SH_C0 = 0.28209479177387814f;
        float colr = fmaxf(SH_C0 * feats[3 * i + 0] + 0.5f, 0.0f);
        float colg = fmaxf(SH_C0 * feats[3 * i + 1] + 0.5f, 0.0f);
        float colb = fmaxf(SH_C0 * feats[3 * i + 2] + 0.5f, 0.0f);

        float opv = ops[i];
        float r2;
        if (valid) {
            // alpha >= 1/255 requires d^2 <= 2*lam_max*ln(255*op) (exact bound)
            r2 = 2.0f * lam * __logf(255.0f * opv) * 1.02f + 0.5f;
        } else {
            px = 0.0f; py = 0.0f; ca = 0.0f; cb = 0.0f; cc = 0.0f;
            opv = 0.0f; r2 = -1.0f;                      // never composited
        }
        radii_out[i] = valid ? ceilf(3.0f * sqrtf(lam)) : 0.0f;

        float4* dst = (float4*)(gS + (size_t)rank * GS);
        dst[0] = make_float4(px, py, ca, cb);
        dst[1] = make_float4(cc, opv, colr, colg);
        dst[2] = make_float4(colb, r2, 0.0f, 0.0f);
    }
}

// ----------------------------------------------------------------- raster
// Block = (tile, chunk); 2048 blocks = 8/CU. One thread per pixel of a
// 16x16 tile; composites `chunk` sorted gaussians into a partial (rgb,T).
// Record loads are block-uniform -> scalar loads; the r2 tile-cull test is
// wave-uniform -> s_cbranch skip, zero divergence.
__global__ void gsplat_raster_chunk(const float* __restrict__ gS, int P,
                                    int chunk, float4* __restrict__ part)
{
    int lx = threadIdx.x & 15, ly = threadIdx.x >> 4;
    int tilex = blockIdx.x & 7, tiley = blockIdx.x >> 3;
    int x = tilex * 16 + lx, y = tiley * 16 + ly;
    float gx = (float)x, gy = (float)y;
    float tx0 = (float)(tilex * 16), tx1 = (float)(tilex * 16 + 15);
    float ty0 = (float)(tiley * 16), ty1 = (float)(tiley * 16 + 15);

    int base = blockIdx.y * chunk;
    int cnt = min(chunk, P - base);

    float T = 1.0f, cr = 0.0f, cg = 0.0f, cb = 0.0f;

    const float* Gp = gS + (size_t)base * GS;
    #pragma unroll 2
    for (int p = 0; p < cnt; ++p) {
        const float* G = Gp + (size_t)p * GS;
        float pxv = G[0], pyv = G[1];
        // block-uniform cull: nearest tile point vs r2 bound
        float ddx = pxv - fminf(fmaxf(pxv, tx0), tx1);
        float ddy = pyv - fminf(fmaxf(pyv, ty0), ty1);
        if (ddx * ddx + ddy * ddy > G[9]) continue;      // uniform branch
        float ca = G[2], cbn = G[3], cc = G[4];
        float op = G[5], r = G[6], g = G[7], b = G[8];
        float dx = gx - pxv, dy = gy - pyv;
        float power = -0.5f * (ca * dx * dx + cc * dy * dy) - cbn * dx * dy;
        float e = __expf(fminf(power, 0.0f));
        float alpha = fminf(0.99f, op * e);
        alpha = (power > 0.0f) ? 0.0f : alpha;
        alpha = (alpha < 0.00392156862745098f) ? 0.0f : alpha;
        float w = T * alpha;
        cr = fmaf(w, r, cr);
        cg = fmaf(w, g, cg);
        cb = fmaf(w, b, cb);
        T = T * (1.0f - alpha);
    }

    int pix = y * IMG + x;
    part[(size_t)blockIdx.y * NPIX + pix] = make_float4(cr, cg, cb, T);
}

// ----------------------------------------------------------------- combine
// Ordered front-to-back merge of K chunk partials per pixel; adds T_final.
__global__ void gsplat_combine(const float4* __restrict__ part, int K,
                               float* __restrict__ img)
{
    int pix = blockIdx.x * blockDim.x + threadIdx.x;
    if (pix >= NPIX) return;
    float T = 1.0f, r = 0.0f, g = 0.0f, b = 0.0f;
    for (int c = 0; c < K; ++c) {
        float4 v = part[(size_t)c * NPIX + pix];
        r = fmaf(T, v.x, r);
        g = fmaf(T, v.y, g);
        b = fmaf(T, v.z, b);
        T *= v.w;
    }
    img[pix]            = r + T;
    img[NPIX + pix]     = g + T;
    img[2 * NPIX + pix] = b + T;
}

// ------------------------------------------------------------------ launch
extern "C" void kernel_launch(void* const* d_in, const int* in_sizes, int n_in,
                              void* d_out, int out_size, void* d_ws, size_t ws_size,
                              hipStream_t stream)
{
    const float* means  = (const float*)d_in[0];
    const float* feats  = (const float*)d_in[2];
    const float* ops    = (const float*)d_in[3];
    const float* scales = (const float*)d_in[4];
    const float* rots   = (const float*)d_in[5];
    const float* vm     = (const float*)d_in[6];
    const float* pm     = (const float*)d_in[7];

    int P = in_sizes[0] / 3;   // 2048

    float* img   = (float*)d_out;            // 3*128*128
    float* radii = (float*)d_out + 3 * NPIX; // P

    float* gS   = (float*)d_ws;                          // SORT_N*GS floats
    float* endf = gS + (size_t)SORT_N * GS;              // 16B-aligned
    size_t static_bytes = (size_t)SORT_N * GS * sizeof(float);
    float4* part = (float4*)endf;

    // Pick K chunks to fit ws: part needs K*NPIX*16 bytes.
    int K = 32;
    while (K > 1 && static_bytes + (size_t)K * NPIX * sizeof(float4) > ws_size) K >>= 1;
    int chunk = (P + K - 1) / K;

    gsplat_prep_rank_scatter<<<(P + 63) / 64, 256, 0, stream>>>(
        means, feats, ops, scales, rots, vm, pm, gS, radii, P);

    gsplat_raster_chunk<<<dim3(64, K), 256, 0, stream>>>(gS, P, chunk, part);

    gsplat_combine<<<NPIX / 256, 256, 0, stream>>>(part, K, img);
}